// Round 15
// baseline (148.681 us; speedup 1.0000x reference)
//
#include <hip/hip_runtime.h>

#define N_NODES 100000
#define NE 500000
#define NEP 100000
#define NBLK_SCAN ((N_NODES + 255) / 256)   // 391

typedef short bf16x8 __attribute__((ext_vector_type(8)));
typedef float f32x4  __attribute__((ext_vector_type(4)));
typedef ushort ushort8v __attribute__((ext_vector_type(8)));

__device__ inline ushort f2bf(float f) {
    uint u = __builtin_bit_cast(uint, f);
    return (ushort)((u + 0x7FFFu + ((u >> 16) & 1u)) >> 16);   // RNE
}
__device__ inline float bf2f(ushort h) {
    uint u = ((uint)h) << 16;
    return __builtin_bit_cast(float, u);
}
__device__ inline float bflo(uint v) { return __builtin_bit_cast(float, v << 16); }
__device__ inline float bfhi(uint v) { return __builtin_bit_cast(float, v & 0xFFFF0000u); }

// ---------------- CSR build ---------------------------------------------------
__global__ __launch_bounds__(256) void hist_kernel(
    const int* __restrict__ ei, int* __restrict__ cnt) {
    int e = blockIdx.x * 256 + threadIdx.x;
    if (e >= NE) return;
    atomicAdd(&cnt[ei[NE + e]], 1);
}

__global__ __launch_bounds__(256) void scan1_kernel(
    const int* __restrict__ cnt, int* __restrict__ off, int* __restrict__ sums) {
    __shared__ int buf[256];
    int t = threadIdx.x;
    int i = blockIdx.x * 256 + t;
    int v = (i < N_NODES) ? cnt[i] : 0;
    buf[t] = v;
    __syncthreads();
#pragma unroll
    for (int d = 1; d < 256; d <<= 1) {
        int add = (t >= d) ? buf[t - d] : 0;
        __syncthreads();
        buf[t] += add;
        __syncthreads();
    }
    if (i < N_NODES) off[i] = buf[t] - v;
    if (t == 255) sums[blockIdx.x] = buf[255];
}

// merged scan2+scan3: each block reduces its own prefix of sums
__global__ __launch_bounds__(256) void scan23_kernel(
    int* __restrict__ off, int* __restrict__ off2, const int* __restrict__ sums) {
    __shared__ int red[256];
    int bid = blockIdx.x, t = threadIdx.x;
    int v = 0;
    if (t < bid) v += sums[t];
    if (t + 256 < bid) v += sums[t + 256];   // bid <= 390 < 512
    red[t] = v;
    __syncthreads();
#pragma unroll
    for (int d = 128; d > 0; d >>= 1) {
        if (t < d) red[t] += red[t + d];
        __syncthreads();
    }
    int pre = red[0];
    int i = bid * 256 + t;
    if (i < N_NODES) {
        int o = off[i] + pre;
        off[i] = o;
        off2[i] = o;
    }
    if (i == 0) off[N_NODES] = NE;
}

__global__ __launch_bounds__(256) void fill_kernel(
    const int* __restrict__ ei, int* __restrict__ off2, int* __restrict__ srcS) {
    int e = blockIdx.x * 256 + threadIdx.x;
    if (e >= NE) return;
    int src = ei[e];
    int dst = ei[NE + e];
    int pos = atomicAdd(&off2[dst], 1);
    srcS[pos] = src;
}

// -------- prep: x->bf16 | pack W1-hi | pack W2-hi | zero cnt -------------------
__global__ __launch_bounds__(256) void prep_kernel(
    const float* __restrict__ x, ushort* __restrict__ xb,
    const float* __restrict__ Wl1, const float* __restrict__ Wr1,
    ushort* __restrict__ b1h,
    const float* __restrict__ Wl2, const float* __restrict__ Wr2,
    ushort* __restrict__ b2h, int* __restrict__ cnt) {
    int b = blockIdx.x;
    if (b < 12500) {
        size_t i = ((size_t)b * 256 + threadIdx.x) * 4;
        float4 v = *reinterpret_cast<const float4*>(x + i);
        ushort4 o;
        o.x = f2bf(v.x); o.y = f2bf(v.y); o.z = f2bf(v.z); o.w = f2bf(v.w);
        *reinterpret_cast<ushort4*>(xb + i) = o;
    } else if (b < 12500 + 128) {
        int gid = (b - 12500) * 256 + threadIdx.x;      // < 32768
        int r = gid & 7, lane = (gid >> 3) & 63, t = (gid >> 9) & 7, ks = gid >> 12;
        int k = ks * 32 + ((lane >> 4) << 3) + r;
        int n = t * 16 + (lane & 15);
        float v = (k < 128) ? Wl1[k * 128 + n] : Wr1[(k - 128) * 128 + n];
        b1h[gid] = f2bf(v);
    } else if (b < 12692) {
        int gid = (b - 12628) * 256 + threadIdx.x;      // < 16384
        int r = gid & 7, lane = (gid >> 3) & 63, t = (gid >> 9) & 7, ks = gid >> 12;
        int k = ks * 32 + ((lane >> 4) << 3) + r;
        int col = t * 16 + (lane & 15);
        float v = (col < 64) ? Wl2[k * 64 + col] : Wr2[k * 64 + (col - 64)];
        b2h[gid] = f2bf(v);
    } else {
        // zero cnt: 98 blocks x 256 threads x 4 ints (overshoot lands in off,
        // which scan1/scan23 rewrite afterwards)
        int i = ((b - 12692) * 256 + threadIdx.x) * 4;
        *reinterpret_cast<int4*>(cnt + i) = make_int4(0, 0, 0, 0);
    }
}

// ------- fused gather-mean + MLP ----------------------------------------------
// 512 threads = 8 waves x 16 rows. Lane (lrow,kg) gathers node r0+lrow's mean
// for channels ks*32+kg*8 directly into MFMA A-frag registers. W1+W2 staged in
// LDS once; ONE barrier; then both GEMMs run wave-independently.
__global__ __launch_bounds__(512) void mlp_kernel(
    const ushort* __restrict__ xb, const int* __restrict__ off,
    const int* __restrict__ srcS,
    const ushort* __restrict__ b1h, const float* __restrict__ b1,
    const ushort* __restrict__ b2h,
    ushort* __restrict__ tb, ushort* __restrict__ ub) {
    __shared__ __align__(16) ushort Ws[49152];     // 96KB: W1 [0,32768), W2 [32768,49152)
    __shared__ __align__(16) ushort hs[8][2048];   // 8 waves x 4KB h tile
    const int tid = threadIdx.x;
    const int w = tid >> 6, lane = tid & 63;
    const int lrow = lane & 15, kg = lane >> 4;
    int wid = blockIdx.x * 8 + w;
    if (wid > N_NODES / 16 - 1) wid = N_NODES / 16 - 1;   // clamp: dup work, same values
    const size_t r0 = (size_t)wid * 16;
    char* hw = (char*)&hs[w][0];
    const f32x4 z4 = {0.f, 0.f, 0.f, 0.f};

    const int n = (int)r0 + lrow;                  // this lane's gather node
    const int s0 = off[n], s1 = off[n + 1];

    // ---- x-part A-frags (own row, coalesced) ----
    bf16x8 aF[8];
#pragma unroll
    for (int ks = 0; ks < 4; ++ks)
        aF[4 + ks] = *(const bf16x8*)(xb + (r0 + lrow) * 128 + ks * 32 + kg * 8);

    // ---- stage all B once (issued before the gather so it drains underneath) ----
    {
        const ushort8v* src1 = (const ushort8v*)b1h;
        const ushort8v* src2 = (const ushort8v*)b2h;
        ushort8v* dst = (ushort8v*)Ws;
#pragma unroll
        for (int i = 0; i < 12; ++i) {
            int j = tid + i * 512;
            dst[j] = (j < 4096) ? src1[j] : src2[j - 4096];
        }
    }

    // ---- gather mean for node n, channels {ks*32+kg*8 .. +8}, ks=0..3 ----
    float ga[4][8];
#pragma unroll
    for (int ks = 0; ks < 4; ++ks)
#pragma unroll
        for (int j = 0; j < 8; ++j) ga[ks][j] = 0.f;
#define ACCG(ks, v)                                                       \
    { ga[ks][0] += bflo((v).x); ga[ks][1] += bfhi((v).x);                 \
      ga[ks][2] += bflo((v).y); ga[ks][3] += bfhi((v).y);                 \
      ga[ks][4] += bflo((v).z); ga[ks][5] += bfhi((v).z);                 \
      ga[ks][6] += bflo((v).w); ga[ks][7] += bfhi((v).w); }
    {
        int k = s0;
        for (; k + 2 <= s1; k += 2) {
            int sA = srcS[k], sB = srcS[k + 1];
            const ushort* rA = xb + (size_t)sA * 128 + kg * 8;
            const ushort* rB = xb + (size_t)sB * 128 + kg * 8;
            uint4 vA0 = *(const uint4*)(rA);
            uint4 vA1 = *(const uint4*)(rA + 32);
            uint4 vA2 = *(const uint4*)(rA + 64);
            uint4 vA3 = *(const uint4*)(rA + 96);
            uint4 vB0 = *(const uint4*)(rB);
            uint4 vB1 = *(const uint4*)(rB + 32);
            uint4 vB2 = *(const uint4*)(rB + 64);
            uint4 vB3 = *(const uint4*)(rB + 96);
            ACCG(0, vA0) ACCG(1, vA1) ACCG(2, vA2) ACCG(3, vA3)
            ACCG(0, vB0) ACCG(1, vB1) ACCG(2, vB2) ACCG(3, vB3)
        }
        if (k < s1) {
            int sA = srcS[k];
            const ushort* rA = xb + (size_t)sA * 128 + kg * 8;
            uint4 vA0 = *(const uint4*)(rA);
            uint4 vA1 = *(const uint4*)(rA + 32);
            uint4 vA2 = *(const uint4*)(rA + 64);
            uint4 vA3 = *(const uint4*)(rA + 96);
            ACCG(0, vA0) ACCG(1, vA1) ACCG(2, vA2) ACCG(3, vA3)
        }
    }
#undef ACCG
    {
        float inv = (s1 > s0) ? 1.0f / (float)(s1 - s0) : 0.0f;
#pragma unroll
        for (int ks = 0; ks < 4; ++ks) {
            bf16x8 f;
#pragma unroll
            for (int j = 0; j < 8; ++j) f[j] = (short)f2bf(ga[ks][j] * inv);
            aF[ks] = f;
        }
    }
    __syncthreads();   // the only barrier (W stage complete)

    // ---- phase A: layer-1 GEMM (K=256: mean | x), all A in registers ----
    f32x4 acc[8];
#pragma unroll
    for (int t = 0; t < 8; ++t) acc[t] = z4;
#pragma unroll
    for (int ks = 0; ks < 8; ++ks) {
#pragma unroll
        for (int t = 0; t < 8; ++t) {
            bf16x8 Bh = *(const bf16x8*)(Ws + (ks * 8 + t) * 512 + lane * 8);
            acc[t] = __builtin_amdgcn_mfma_f32_16x16x32_bf16(aF[ks], Bh, acc[t], 0, 0, 0);
        }
    }

    // ---- epilogue A: bias + relu -> swizzled wave-private LDS h tile ----
#pragma unroll
    for (int t = 0; t < 8; ++t) {
        float bj = b1[t * 16 + lrow];
#pragma unroll
        for (int rg = 0; rg < 4; ++rg) {
            int row = kg * 4 + rg;
            int col2 = (t * 16 + lrow) * 2;
            int byte = row * 256 + (col2 ^ ((row & 7) << 4));
            *(ushort*)(hw + byte) = f2bf(fmaxf(acc[t][rg] + bj, 0.0f));
        }
    }

    // ---- phase B: layer-2 GEMM from LDS h (K=128), h-frags prefetched ----
    bf16x8 hF[4];
#pragma unroll
    for (int ks = 0; ks < 4; ++ks) {
        int byte = lrow * 256 + ((ks * 64 + kg * 16) ^ ((lrow & 7) << 4));
        hF[ks] = *(const bf16x8*)(hw + byte);
    }
    f32x4 acc2[8];
#pragma unroll
    for (int t = 0; t < 8; ++t) acc2[t] = z4;
#pragma unroll
    for (int ks = 0; ks < 4; ++ks) {
#pragma unroll
        for (int t = 0; t < 8; ++t) {
            bf16x8 Bh = *(const bf16x8*)(Ws + 32768 + (ks * 8 + t) * 512 + lane * 8);
            acc2[t] = __builtin_amdgcn_mfma_f32_16x16x32_bf16(hF[ks], Bh, acc2[t], 0, 0, 0);
        }
    }

    // ---- epilogue B: write t|u ----
#pragma unroll
    for (int t = 0; t < 8; ++t) {
#pragma unroll
        for (int rg = 0; rg < 4; ++rg) {
            size_t row = r0 + kg * 4 + rg;
            int col = t * 16 + lrow;
            if (t < 4) tb[row * 64 + col] = f2bf(acc2[t][rg]);
            else       ub[row * 64 + (col - 64)] = f2bf(acc2[t][rg]);
        }
    }
}

// ------- layer-2 gather: 8 lanes/node, 16B loads ------------------------------
__global__ __launch_bounds__(256) void agg_z_kernel(
    const ushort* __restrict__ tb, const ushort* __restrict__ ub,
    const float* __restrict__ b2, const int* __restrict__ off,
    const int* __restrict__ srcS, ushort* __restrict__ zb) {
    int n = blockIdx.x * 32 + (threadIdx.x >> 3);   // 32 nodes per block
    if (n >= N_NODES) return;
    int l = threadIdx.x & 7;                        // channels 8l..8l+7
    int s0 = off[n], s1 = off[n + 1];
    float a0 = 0.f, a1 = 0.f, a2 = 0.f, a3 = 0.f;
    float a4 = 0.f, a5 = 0.f, a6 = 0.f, a7 = 0.f;
    int k = s0;
#define ACCZ(v)                                                   \
    { a0 += bflo((v).x); a1 += bfhi((v).x);                       \
      a2 += bflo((v).y); a3 += bfhi((v).y);                       \
      a4 += bflo((v).z); a5 += bfhi((v).z);                       \
      a6 += bflo((v).w); a7 += bfhi((v).w); }
    for (; k + 4 <= s1; k += 4) {
        int sa = srcS[k], sb = srcS[k + 1], sc = srcS[k + 2], sd = srcS[k + 3];
        uint4 va = *(const uint4*)(tb + (size_t)sa * 64 + l * 8);
        uint4 vb = *(const uint4*)(tb + (size_t)sb * 64 + l * 8);
        uint4 vc = *(const uint4*)(tb + (size_t)sc * 64 + l * 8);
        uint4 vd = *(const uint4*)(tb + (size_t)sd * 64 + l * 8);
        ACCZ(va) ACCZ(vb) ACCZ(vc) ACCZ(vd)
    }
    for (; k < s1; ++k) {
        uint4 v = *(const uint4*)(tb + (size_t)srcS[k] * 64 + l * 8);
        ACCZ(v)
    }
#undef ACCZ
    float inv = (s1 > s0) ? 1.0f / (float)(s1 - s0) : 0.0f;
    uint4 uu = *(const uint4*)(ub + (size_t)n * 64 + l * 8);
    const float* bp = b2 + l * 8;
    uint4 o;
    o.x = (uint)f2bf(a0 * inv + bflo(uu.x) + bp[0]) | ((uint)f2bf(a1 * inv + bfhi(uu.x) + bp[1]) << 16);
    o.y = (uint)f2bf(a2 * inv + bflo(uu.y) + bp[2]) | ((uint)f2bf(a3 * inv + bfhi(uu.y) + bp[3]) << 16);
    o.z = (uint)f2bf(a4 * inv + bflo(uu.z) + bp[4]) | ((uint)f2bf(a5 * inv + bfhi(uu.z) + bp[5]) << 16);
    o.w = (uint)f2bf(a6 * inv + bflo(uu.w) + bp[6]) | ((uint)f2bf(a7 * inv + bfhi(uu.w) + bp[7]) << 16);
    *(uint4*)(zb + (size_t)n * 64 + l * 8) = o;
}

// ---------------- decode over bf16 z: 8 lanes/edge ----------------------------
__global__ __launch_bounds__(256) void decode_kernel(
    const ushort* __restrict__ zb,
    const int* __restrict__ pos, const int* __restrict__ neg,
    float* __restrict__ out) {
    int t = blockIdx.x * 256 + threadIdx.x;
    int g = t >> 3;
    int lane = t & 7;
    if (g >= 2 * NEP) return;
    const int* ei;
    int e;
    float* o;
    if (g < NEP) { ei = pos; e = g; o = out; }
    else         { ei = neg; e = g - NEP; o = out + NEP; }
    int a  = ei[e];
    int bn = ei[NEP + e];
    uint4 va = *reinterpret_cast<const uint4*>(zb + (size_t)a  * 64 + lane * 8);
    uint4 vb = *reinterpret_cast<const uint4*>(zb + (size_t)bn * 64 + lane * 8);
    float s = bflo(va.x) * bflo(vb.x) + bfhi(va.x) * bfhi(vb.x)
            + bflo(va.y) * bflo(vb.y) + bfhi(va.y) * bfhi(vb.y)
            + bflo(va.z) * bflo(vb.z) + bfhi(va.z) * bfhi(vb.z)
            + bflo(va.w) * bflo(vb.w) + bfhi(va.w) * bfhi(vb.w);
    s += __shfl_xor(s, 1);
    s += __shfl_xor(s, 2);
    s += __shfl_xor(s, 4);
    if (lane == 0) o[e] = s;
}

extern "C" void kernel_launch(void* const* d_in, const int* in_sizes, int n_in,
                              void* d_out, int out_size, void* d_ws, size_t ws_size,
                              hipStream_t stream) {
    const float* x    = (const float*)d_in[0];
    const int*   ei   = (const int*)d_in[1];
    const int*   pos  = (const int*)d_in[2];
    const int*   neg  = (const int*)d_in[3];
    const float* Wl1  = (const float*)d_in[4];
    const float* Wr1  = (const float*)d_in[5];
    const float* b1   = (const float*)d_in[6];
    const float* Wl2  = (const float*)d_in[7];
    const float* Wr2  = (const float*)d_in[8];
    const float* b2   = (const float*)d_in[9];
    float* out = (float*)d_out;

    const size_t HALF = (size_t)N_NODES * 128 * 2;   // 25.6 MB (one bf16 plane)
    const size_t QTR  = (size_t)N_NODES * 64 * 2;    // 12.8 MB
    char* ws = (char*)d_ws;
    ushort* xb    = (ushort*)ws;                     // N*128 bf16
    ushort* tb    = (ushort*)(ws + 2 * HALF);                 // N*64 bf16
    ushort* ub    = (ushort*)(ws + 2 * HALF + QTR);           // N*64 bf16
    ushort* zb    = (ushort*)(ws + 2 * HALF + 2 * QTR);       // N*64 bf16
    // ints + packed weights
    int* cnt  = (int*)(ws + 2 * HALF + 3 * QTR);
    int* off  = cnt + N_NODES;
    int* off2 = off + N_NODES + 1;
    int* srcS = off2 + N_NODES;
    int* sums = srcS + NE;
    ushort* b1h = (ushort*)(sums + 512);   // 32768 ushorts
    ushort* b2h = b1h + 32768;             // 16384 ushorts

    // ---- prep: x->bf16 + weight packing + cnt zero ----
    prep_kernel<<<12790, 256, 0, stream>>>(x, xb, Wl1, Wr1, b1h, Wl2, Wr2, b2h, cnt);

    // ---- CSR build ----
    hist_kernel <<<(NE + 255) / 256, 256, 0, stream>>>(ei, cnt);
    scan1_kernel<<<NBLK_SCAN, 256, 0, stream>>>(cnt, off, sums);
    scan23_kernel<<<NBLK_SCAN, 256, 0, stream>>>(off, off2, sums);
    fill_kernel <<<(NE + 255) / 256, 256, 0, stream>>>(ei, off2, srcS);

    // ---- fused gather-mean + MLP ----
    mlp_kernel<<<(N_NODES / 16 + 7) / 8, 512, 0, stream>>>(
        xb, off, srcS, b1h, b1, b2h, tb, ub);

    // ---- layer 2 aggregate + combine ----
    agg_z_kernel<<<N_NODES / 32 + 1, 256, 0, stream>>>(tb, ub, b2, off, srcS, zb);

    // ---- decode ----
    decode_kernel<<<(2 * NEP * 8 + 255) / 256, 256, 0, stream>>>(zb, pos, neg, out);
}

// Round 16
// 141.315 us; speedup vs baseline: 1.0521x; 1.0521x over previous
//
#include <hip/hip_runtime.h>

#define N_NODES 100000
#define NE 500000
#define NEP 100000
#define NBLK_SCAN ((N_NODES + 255) / 256)   // 391

typedef short bf16x8 __attribute__((ext_vector_type(8)));
typedef float f32x4  __attribute__((ext_vector_type(4)));
typedef ushort ushort8v __attribute__((ext_vector_type(8)));

__device__ inline ushort f2bf(float f) {
    uint u = __builtin_bit_cast(uint, f);
    return (ushort)((u + 0x7FFFu + ((u >> 16) & 1u)) >> 16);   // RNE
}
__device__ inline float bf2f(ushort h) {
    uint u = ((uint)h) << 16;
    return __builtin_bit_cast(float, u);
}
__device__ inline float bflo(uint v) { return __builtin_bit_cast(float, v << 16); }
__device__ inline float bfhi(uint v) { return __builtin_bit_cast(float, v & 0xFFFF0000u); }

// ---------------- CSR build ---------------------------------------------------
__global__ __launch_bounds__(256) void hist_kernel(
    const int* __restrict__ ei, int* __restrict__ cnt) {
    int e = blockIdx.x * 256 + threadIdx.x;
    if (e >= NE) return;
    atomicAdd(&cnt[ei[NE + e]], 1);
}

__global__ __launch_bounds__(256) void scan1_kernel(
    const int* __restrict__ cnt, int* __restrict__ off, int* __restrict__ sums) {
    __shared__ int buf[256];
    int t = threadIdx.x;
    int i = blockIdx.x * 256 + t;
    int v = (i < N_NODES) ? cnt[i] : 0;
    buf[t] = v;
    __syncthreads();
#pragma unroll
    for (int d = 1; d < 256; d <<= 1) {
        int add = (t >= d) ? buf[t - d] : 0;
        __syncthreads();
        buf[t] += add;
        __syncthreads();
    }
    if (i < N_NODES) off[i] = buf[t] - v;
    if (t == 255) sums[blockIdx.x] = buf[255];
}

// merged scan2+scan3: each block reduces its own prefix of sums
__global__ __launch_bounds__(256) void scan23_kernel(
    int* __restrict__ off, int* __restrict__ off2, const int* __restrict__ sums) {
    __shared__ int red[256];
    int bid = blockIdx.x, t = threadIdx.x;
    int v = 0;
    if (t < bid) v += sums[t];
    if (t + 256 < bid) v += sums[t + 256];   // bid <= 390 < 512
    red[t] = v;
    __syncthreads();
#pragma unroll
    for (int d = 128; d > 0; d >>= 1) {
        if (t < d) red[t] += red[t + d];
        __syncthreads();
    }
    int pre = red[0];
    int i = bid * 256 + t;
    if (i < N_NODES) {
        int o = off[i] + pre;
        off[i] = o;
        off2[i] = o;
    }
    if (i == 0) off[N_NODES] = NE;
}

__global__ __launch_bounds__(256) void fill_kernel(
    const int* __restrict__ ei, int* __restrict__ off2, int* __restrict__ srcS) {
    int e = blockIdx.x * 256 + threadIdx.x;
    if (e >= NE) return;
    int src = ei[e];
    int dst = ei[NE + e];
    int pos = atomicAdd(&off2[dst], 1);
    srcS[pos] = src;
}

// -------- prep: x->bf16 (32B/thread) | pack W1-hi | pack W2-hi | zero cnt ------
__global__ __launch_bounds__(256) void prep_kernel(
    const float* __restrict__ x, ushort* __restrict__ xb,
    const float* __restrict__ Wl1, const float* __restrict__ Wr1,
    ushort* __restrict__ b1h,
    const float* __restrict__ Wl2, const float* __restrict__ Wr2,
    ushort* __restrict__ b2h, int* __restrict__ cnt) {
    int b = blockIdx.x;
    if (b < 6250) {
        size_t i = ((size_t)b * 256 + threadIdx.x) * 8;   // 12.8M elems exact
        float4 v0 = *reinterpret_cast<const float4*>(x + i);
        float4 v1 = *reinterpret_cast<const float4*>(x + i + 4);
        ushort8v o;
        o[0] = f2bf(v0.x); o[1] = f2bf(v0.y); o[2] = f2bf(v0.z); o[3] = f2bf(v0.w);
        o[4] = f2bf(v1.x); o[5] = f2bf(v1.y); o[6] = f2bf(v1.z); o[7] = f2bf(v1.w);
        *reinterpret_cast<ushort8v*>(xb + i) = o;
    } else if (b < 6250 + 128) {
        int gid = (b - 6250) * 256 + threadIdx.x;       // < 32768
        int r = gid & 7, lane = (gid >> 3) & 63, t = (gid >> 9) & 7, ks = gid >> 12;
        int k = ks * 32 + ((lane >> 4) << 3) + r;
        int n = t * 16 + (lane & 15);
        float v = (k < 128) ? Wl1[k * 128 + n] : Wr1[(k - 128) * 128 + n];
        b1h[gid] = f2bf(v);
    } else if (b < 6442) {
        int gid = (b - 6378) * 256 + threadIdx.x;       // < 16384
        int r = gid & 7, lane = (gid >> 3) & 63, t = (gid >> 9) & 7, ks = gid >> 12;
        int k = ks * 32 + ((lane >> 4) << 3) + r;
        int col = t * 16 + (lane & 15);
        float v = (col < 64) ? Wl2[k * 64 + col] : Wr2[k * 64 + (col - 64)];
        b2h[gid] = f2bf(v);
    } else {
        // zero cnt: 98 blocks x 256 threads x 4 ints (overshoot lands in off,
        // which scan1/scan23 rewrite afterwards)
        int i = ((b - 6442) * 256 + threadIdx.x) * 4;
        *reinterpret_cast<int4*>(cnt + i) = make_int4(0, 0, 0, 0);
    }
}

// ------- layer-1 gather mean: 16 lanes/node, uint4 (16B) loads ----------------
__global__ __launch_bounds__(256) void agg_mean_kernel(
    const ushort* __restrict__ xb, const int* __restrict__ off,
    const int* __restrict__ srcS, ushort* __restrict__ meanH) {
    int n = blockIdx.x * 16 + (threadIdx.x >> 4);   // 100000/16 = 6250 exact
    int l = threadIdx.x & 15;                       // channels 8l..8l+7
    int s0 = off[n], s1 = off[n + 1];
    float a0 = 0.f, a1 = 0.f, a2 = 0.f, a3 = 0.f;
    float a4 = 0.f, a5 = 0.f, a6 = 0.f, a7 = 0.f;
    int k = s0;
#define ACCM(v)                                                   \
    { a0 += bflo((v).x); a1 += bfhi((v).x);                       \
      a2 += bflo((v).y); a3 += bfhi((v).y);                       \
      a4 += bflo((v).z); a5 += bfhi((v).z);                       \
      a6 += bflo((v).w); a7 += bfhi((v).w); }
    for (; k + 4 <= s1; k += 4) {
        int sa = srcS[k], sb = srcS[k + 1], sc = srcS[k + 2], sd = srcS[k + 3];
        uint4 va = *(const uint4*)(xb + (size_t)sa * 128 + l * 8);
        uint4 vb = *(const uint4*)(xb + (size_t)sb * 128 + l * 8);
        uint4 vc = *(const uint4*)(xb + (size_t)sc * 128 + l * 8);
        uint4 vd = *(const uint4*)(xb + (size_t)sd * 128 + l * 8);
        ACCM(va) ACCM(vb) ACCM(vc) ACCM(vd)
    }
    for (; k < s1; ++k) {
        uint4 v = *(const uint4*)(xb + (size_t)srcS[k] * 128 + l * 8);
        ACCM(v)
    }
#undef ACCM
    float inv = (s1 > s0) ? 1.0f / (float)(s1 - s0) : 0.0f;
    uint4 o;
    o.x = (uint)f2bf(a0 * inv) | ((uint)f2bf(a1 * inv) << 16);
    o.y = (uint)f2bf(a2 * inv) | ((uint)f2bf(a3 * inv) << 16);
    o.z = (uint)f2bf(a4 * inv) | ((uint)f2bf(a5 * inv) << 16);
    o.w = (uint)f2bf(a6 * inv) | ((uint)f2bf(a7 * inv) << 16);
    *(uint4*)(meanH + (size_t)n * 128 + l * 8) = o;
}

// ------- fused MLP: prefetch A-frags, stage W1+W2 hi once, ONE barrier --------
__global__ __launch_bounds__(512) void mlp_kernel(
    const ushort* __restrict__ meanH, const ushort* __restrict__ xb,
    const ushort* __restrict__ b1h, const float* __restrict__ b1,
    const ushort* __restrict__ b2h,
    ushort* __restrict__ tb, ushort* __restrict__ ub) {
    __shared__ __align__(16) ushort Ws[49152];     // 96KB: W1 [0,32768), W2 [32768,49152)
    __shared__ __align__(16) ushort hs[8][2048];   // 8 waves x 4KB h tile
    const int tid = threadIdx.x;
    const int w = tid >> 6, lane = tid & 63;
    const int lrow = lane & 15, kg = lane >> 4;
    int wid = blockIdx.x * 8 + w;
    if (wid > N_NODES / 16 - 1) wid = N_NODES / 16 - 1;   // clamp: dup work, same values
    const size_t r0 = (size_t)wid * 16;
    char* hw = (char*)&hs[w][0];
    const f32x4 z4 = {0.f, 0.f, 0.f, 0.f};

    // ---- T14: issue all 8 A-frag global loads BEFORE the LDS stage ----
    bf16x8 aF[8];
#pragma unroll
    for (int ks = 0; ks < 4; ++ks)
        aF[ks] = *(const bf16x8*)(meanH + (r0 + lrow) * 128 + ks * 32 + kg * 8);
#pragma unroll
    for (int ks = 0; ks < 4; ++ks)
        aF[4 + ks] = *(const bf16x8*)(xb + (r0 + lrow) * 128 + ks * 32 + kg * 8);

    // ---- stage all B once (6144 x 16B chunks) ----
    {
        const ushort8v* src1 = (const ushort8v*)b1h;
        const ushort8v* src2 = (const ushort8v*)b2h;
        ushort8v* dst = (ushort8v*)Ws;
#pragma unroll
        for (int i = 0; i < 12; ++i) {
            int j = tid + i * 512;
            dst[j] = (j < 4096) ? src1[j] : src2[j - 4096];
        }
    }
    __syncthreads();   // the only barrier

    // ---- phase A: layer-1 GEMM (K=256: mean | x), all A in registers ----
    f32x4 acc[8];
#pragma unroll
    for (int t = 0; t < 8; ++t) acc[t] = z4;
#pragma unroll
    for (int ks = 0; ks < 8; ++ks) {
#pragma unroll
        for (int t = 0; t < 8; ++t) {
            bf16x8 Bh = *(const bf16x8*)(Ws + (ks * 8 + t) * 512 + lane * 8);
            acc[t] = __builtin_amdgcn_mfma_f32_16x16x32_bf16(aF[ks], Bh, acc[t], 0, 0, 0);
        }
    }

    // ---- epilogue A: bias + relu -> swizzled wave-private LDS h tile ----
#pragma unroll
    for (int t = 0; t < 8; ++t) {
        float bj = b1[t * 16 + lrow];
#pragma unroll
        for (int rg = 0; rg < 4; ++rg) {
            int row = kg * 4 + rg;
            int col2 = (t * 16 + lrow) * 2;
            int byte = row * 256 + (col2 ^ ((row & 7) << 4));
            *(ushort*)(hw + byte) = f2bf(fmaxf(acc[t][rg] + bj, 0.0f));
        }
    }

    // ---- phase B: layer-2 GEMM from LDS h (K=128), h-frags prefetched ----
    bf16x8 hF[4];
#pragma unroll
    for (int ks = 0; ks < 4; ++ks) {
        int byte = lrow * 256 + ((ks * 64 + kg * 16) ^ ((lrow & 7) << 4));
        hF[ks] = *(const bf16x8*)(hw + byte);
    }
    f32x4 acc2[8];
#pragma unroll
    for (int t = 0; t < 8; ++t) acc2[t] = z4;
#pragma unroll
    for (int ks = 0; ks < 4; ++ks) {
#pragma unroll
        for (int t = 0; t < 8; ++t) {
            bf16x8 Bh = *(const bf16x8*)(Ws + 32768 + (ks * 8 + t) * 512 + lane * 8);
            acc2[t] = __builtin_amdgcn_mfma_f32_16x16x32_bf16(hF[ks], Bh, acc2[t], 0, 0, 0);
        }
    }

    // ---- epilogue B: write t|u ----
#pragma unroll
    for (int t = 0; t < 8; ++t) {
#pragma unroll
        for (int rg = 0; rg < 4; ++rg) {
            size_t row = r0 + kg * 4 + rg;
            int col = t * 16 + lrow;
            if (t < 4) tb[row * 64 + col] = f2bf(acc2[t][rg]);
            else       ub[row * 64 + (col - 64)] = f2bf(acc2[t][rg]);
        }
    }
}

// ------- layer-2 gather: 8 lanes/node, 16B loads ------------------------------
__global__ __launch_bounds__(256) void agg_z_kernel(
    const ushort* __restrict__ tb, const ushort* __restrict__ ub,
    const float* __restrict__ b2, const int* __restrict__ off,
    const int* __restrict__ srcS, ushort* __restrict__ zb) {
    int n = blockIdx.x * 32 + (threadIdx.x >> 3);   // 32 nodes per block
    if (n >= N_NODES) return;
    int l = threadIdx.x & 7;                        // channels 8l..8l+7
    int s0 = off[n], s1 = off[n + 1];
    float a0 = 0.f, a1 = 0.f, a2 = 0.f, a3 = 0.f;
    float a4 = 0.f, a5 = 0.f, a6 = 0.f, a7 = 0.f;
    int k = s0;
#define ACCZ(v)                                                   \
    { a0 += bflo((v).x); a1 += bfhi((v).x);                       \
      a2 += bflo((v).y); a3 += bfhi((v).y);                       \
      a4 += bflo((v).z); a5 += bfhi((v).z);                       \
      a6 += bflo((v).w); a7 += bfhi((v).w); }
    for (; k + 4 <= s1; k += 4) {
        int sa = srcS[k], sb = srcS[k + 1], sc = srcS[k + 2], sd = srcS[k + 3];
        uint4 va = *(const uint4*)(tb + (size_t)sa * 64 + l * 8);
        uint4 vb = *(const uint4*)(tb + (size_t)sb * 64 + l * 8);
        uint4 vc = *(const uint4*)(tb + (size_t)sc * 64 + l * 8);
        uint4 vd = *(const uint4*)(tb + (size_t)sd * 64 + l * 8);
        ACCZ(va) ACCZ(vb) ACCZ(vc) ACCZ(vd)
    }
    for (; k < s1; ++k) {
        uint4 v = *(const uint4*)(tb + (size_t)srcS[k] * 64 + l * 8);
        ACCZ(v)
    }
#undef ACCZ
    float inv = (s1 > s0) ? 1.0f / (float)(s1 - s0) : 0.0f;
    uint4 uu = *(const uint4*)(ub + (size_t)n * 64 + l * 8);
    const float* bp = b2 + l * 8;
    uint4 o;
    o.x = (uint)f2bf(a0 * inv + bflo(uu.x) + bp[0]) | ((uint)f2bf(a1 * inv + bfhi(uu.x) + bp[1]) << 16);
    o.y = (uint)f2bf(a2 * inv + bflo(uu.y) + bp[2]) | ((uint)f2bf(a3 * inv + bfhi(uu.y) + bp[3]) << 16);
    o.z = (uint)f2bf(a4 * inv + bflo(uu.z) + bp[4]) | ((uint)f2bf(a5 * inv + bfhi(uu.z) + bp[5]) << 16);
    o.w = (uint)f2bf(a6 * inv + bflo(uu.w) + bp[6]) | ((uint)f2bf(a7 * inv + bfhi(uu.w) + bp[7]) << 16);
    *(uint4*)(zb + (size_t)n * 64 + l * 8) = o;
}

// ---------------- decode over bf16 z: 4 lanes/edge, 32B/lane -------------------
__global__ __launch_bounds__(256) void decode_kernel(
    const ushort* __restrict__ zb,
    const int* __restrict__ pos, const int* __restrict__ neg,
    float* __restrict__ out) {
    int t = blockIdx.x * 256 + threadIdx.x;
    int g = t >> 2;
    int lane = t & 3;
    if (g >= 2 * NEP) return;
    const int* ei;
    int e;
    float* o;
    if (g < NEP) { ei = pos; e = g; o = out; }
    else         { ei = neg; e = g - NEP; o = out + NEP; }
    int a  = ei[e];
    int bn = ei[NEP + e];
    const ushort* ra = zb + (size_t)a  * 64 + lane * 16;
    const ushort* rb = zb + (size_t)bn * 64 + lane * 16;
    uint4 va0 = *reinterpret_cast<const uint4*>(ra);
    uint4 va1 = *reinterpret_cast<const uint4*>(ra + 8);
    uint4 vb0 = *reinterpret_cast<const uint4*>(rb);
    uint4 vb1 = *reinterpret_cast<const uint4*>(rb + 8);
    float s = bflo(va0.x) * bflo(vb0.x) + bfhi(va0.x) * bfhi(vb0.x)
            + bflo(va0.y) * bflo(vb0.y) + bfhi(va0.y) * bfhi(vb0.y)
            + bflo(va0.z) * bflo(vb0.z) + bfhi(va0.z) * bfhi(vb0.z)
            + bflo(va0.w) * bflo(vb0.w) + bfhi(va0.w) * bfhi(vb0.w)
            + bflo(va1.x) * bflo(vb1.x) + bfhi(va1.x) * bfhi(vb1.x)
            + bflo(va1.y) * bflo(vb1.y) + bfhi(va1.y) * bfhi(vb1.y)
            + bflo(va1.z) * bflo(vb1.z) + bfhi(va1.z) * bfhi(vb1.z)
            + bflo(va1.w) * bflo(vb1.w) + bfhi(va1.w) * bfhi(vb1.w);
    s += __shfl_xor(s, 1);
    s += __shfl_xor(s, 2);
    if (lane == 0) o[e] = s;
}

extern "C" void kernel_launch(void* const* d_in, const int* in_sizes, int n_in,
                              void* d_out, int out_size, void* d_ws, size_t ws_size,
                              hipStream_t stream) {
    const float* x    = (const float*)d_in[0];
    const int*   ei   = (const int*)d_in[1];
    const int*   pos  = (const int*)d_in[2];
    const int*   neg  = (const int*)d_in[3];
    const float* Wl1  = (const float*)d_in[4];
    const float* Wr1  = (const float*)d_in[5];
    const float* b1   = (const float*)d_in[6];
    const float* Wl2  = (const float*)d_in[7];
    const float* Wr2  = (const float*)d_in[8];
    const float* b2   = (const float*)d_in[9];
    float* out = (float*)d_out;

    const size_t HALF = (size_t)N_NODES * 128 * 2;   // 25.6 MB (one bf16 plane)
    const size_t QTR  = (size_t)N_NODES * 64 * 2;    // 12.8 MB
    char* ws = (char*)d_ws;
    ushort* xb    = (ushort*)ws;                     // N*128 bf16
    ushort* meanH = (ushort*)(ws + HALF);            // N*128 bf16
    ushort* tb    = (ushort*)(ws + 2 * HALF);                 // N*64 bf16
    ushort* ub    = (ushort*)(ws + 2 * HALF + QTR);           // N*64 bf16
    ushort* zb    = (ushort*)(ws + 2 * HALF + 2 * QTR);       // N*64 bf16
    // ints + packed weights
    int* cnt  = (int*)(ws + 2 * HALF + 3 * QTR);
    int* off  = cnt + N_NODES;
    int* off2 = off + N_NODES + 1;
    int* srcS = off2 + N_NODES;
    int* sums = srcS + NE;
    ushort* b1h = (ushort*)(sums + 512);   // 32768 ushorts
    ushort* b2h = b1h + 32768;             // 16384 ushorts

    // ---- prep: x->bf16 + weight packing + cnt zero ----
    prep_kernel<<<6540, 256, 0, stream>>>(x, xb, Wl1, Wr1, b1h, Wl2, Wr2, b2h, cnt);

    // ---- CSR build ----
    hist_kernel <<<(NE + 255) / 256, 256, 0, stream>>>(ei, cnt);
    scan1_kernel<<<NBLK_SCAN, 256, 0, stream>>>(cnt, off, sums);
    scan23_kernel<<<NBLK_SCAN, 256, 0, stream>>>(off, off2, sums);
    fill_kernel <<<(NE + 255) / 256, 256, 0, stream>>>(ei, off2, srcS);

    // ---- layer 1 aggregate ----
    agg_mean_kernel<<<N_NODES / 16, 256, 0, stream>>>(xb, off, srcS, meanH);

    // ---- fused MLP: stage-once LDS B, one barrier ----
    mlp_kernel<<<(N_NODES / 16 + 7) / 8, 512, 0, stream>>>(
        meanH, xb, b1h, b1, b2h, tb, ub);

    // ---- layer 2 aggregate + combine ----
    agg_z_kernel<<<N_NODES / 32 + 1, 256, 0, stream>>>(tb, ub, b2, off, srcS, zb);

    // ---- decode ----
    decode_kernel<<<(2 * NEP * 4 + 255) / 256, 256, 0, stream>>>(zb, pos, neg, out);
}